// Round 9
// baseline (263.330 us; speedup 1.0000x reference)
//
#include <hip/hip_runtime.h>
#include <hip/hip_bf16.h>
#include <stdint.h>

#define BATCH 4
#define TLEN  4096
#define DDIM  1024
#define NCOND 512
#define LDIM  768
#define NHEAD 8
#define HD    128

typedef __bf16 bf16x8 __attribute__((ext_vector_type(8)));
typedef float  f32x4  __attribute__((ext_vector_type(4)));

__device__ __forceinline__ unsigned short f2b(float f) {
    unsigned int u = __builtin_bit_cast(unsigned int, f);
    unsigned int r = (u + 0x7fffu + ((u >> 16) & 1u)) >> 16;
    return (unsigned short)r;
}
__device__ __forceinline__ float b2f(unsigned short s) {
    unsigned int u = ((unsigned int)s) << 16;
    return __builtin_bit_cast(float, u);
}

__device__ __forceinline__ void gl2lds(const void* g, void* l) {
    __builtin_amdgcn_global_load_lds(
        (const __attribute__((address_space(1))) void*)(uintptr_t)g,
        (__attribute__((address_space(3))) void*)(uintptr_t)l,
        16, 0, 0);
}

// ---------------- LN row body: one wave per row ----------------
template<int NCH>
__device__ __forceinline__ void ln_row(const float* __restrict__ x,
    const float* __restrict__ g, const float* __restrict__ bb,
    unsigned short* __restrict__ o, long r, int lane)
{
    const int rowlen = NCH * 256;
    const float* p = x + r * (long)rowlen;
    float4 v[NCH];
    float s = 0.f, ss = 0.f;
#pragma unroll
    for (int i = 0; i < NCH; i++) {
        v[i] = *(const float4*)(p + i * 256 + lane * 4);
        s  += v[i].x + v[i].y + v[i].z + v[i].w;
        ss += v[i].x * v[i].x + v[i].y * v[i].y + v[i].z * v[i].z + v[i].w * v[i].w;
    }
#pragma unroll
    for (int off = 32; off; off >>= 1) {
        s  += __shfl_xor(s,  off, 64);
        ss += __shfl_xor(ss, off, 64);
    }
    float mu = s / rowlen;
    float rs = rsqrtf(fmaxf(ss / rowlen - mu * mu, 0.f) + 1e-5f);
    unsigned short* po = o + r * (long)rowlen;
#pragma unroll
    for (int i = 0; i < NCH; i++) {
        int c = i * 256 + lane * 4;
        float4 gv = *(const float4*)(g + c);
        float4 bv = *(const float4*)(bb + c);
        ushort4 o4;
        o4.x = f2b((v[i].x - mu) * rs * gv.x + bv.x);
        o4.y = f2b((v[i].y - mu) * rs * gv.y + bv.y);
        o4.z = f2b((v[i].z - mu) * rs * gv.z + bv.z);
        o4.w = f2b((v[i].w - mu) * rs * gv.w + bv.w);
        *(ushort4*)(po + c) = o4;
    }
}

// ---------------- prep: ln(x), ln(cond), 3x wtrans (64x64 vectorized) ------
// blocks [0,4096): ln_x | [4096,4608): ln_cond | [4608,5248): wtrans 64x64
// wtrans: float4 reads (16B/lane), ushort4 writes (8B/lane) — G13.
__global__ __launch_bounds__(256) void prep(
    const float* __restrict__ x, const float* __restrict__ ln_g,
    const float* __restrict__ ln_b,
    const float* __restrict__ cond, const float* __restrict__ tln_g,
    const float* __restrict__ tln_b,
    const float* __restrict__ Wq, const float* __restrict__ Wk,
    const float* __restrict__ Wv,
    unsigned short* __restrict__ xn, unsigned short* __restrict__ cn,
    unsigned short* __restrict__ wqT, unsigned short* __restrict__ wkvT)
{
    int blk = blockIdx.x;
    int tid = threadIdx.x, wid = tid >> 6, lane = tid & 63;
    if (blk < 4096) {
        ln_row<4>(x, ln_g, ln_b, xn, (long)blk * 4 + wid, lane);
        return;
    }
    if (blk < 4608) {
        ln_row<3>(cond, tln_g, tln_b, cn, (long)(blk - 4096) * 4 + wid, lane);
        return;
    }
    // 64x64 transpose tiles. Wq: 16 kt x 16 nt = 256 blocks;
    // Wk/Wv: 12 kt x 16 nt = 192 blocks each. total 640.
    int w = blk - 4608;                 // 0..639
    const float* W; unsigned short* Wt; int K, wi;
    if (w < 256)      { W = Wq; Wt = wqT;               K = DDIM; wi = w; }
    else if (w < 448) { W = Wk; Wt = wkvT;              K = LDIM; wi = w - 256; }
    else              { W = Wv; Wt = wkvT + 768 * 1024; K = LDIM; wi = w - 448; }
    int n0 = (wi & 15) * 64, k0 = (wi >> 4) * 64;
    __shared__ float t[64][65];
    int tx4 = (tid & 15) * 4, ty = tid >> 4;    // 16 rows per pass
#pragma unroll
    for (int i = 0; i < 4; i++) {
        int kr = ty + i * 16;
        float4 v4 = *(const float4*)&W[(long)(k0 + kr) * DDIM + n0 + tx4];
        t[kr][tx4 + 0] = v4.x; t[kr][tx4 + 1] = v4.y;
        t[kr][tx4 + 2] = v4.z; t[kr][tx4 + 3] = v4.w;
    }
    __syncthreads();
#pragma unroll
    for (int i = 0; i < 4; i++) {
        int nr = ty + i * 16;
        ushort4 o4;
        o4.x = f2b(t[tx4 + 0][nr]); o4.y = f2b(t[tx4 + 1][nr]);
        o4.z = f2b(t[tx4 + 2][nr]); o4.w = f2b(t[tx4 + 3][nr]);
        *(ushort4*)&Wt[(long)(n0 + nr) * K + k0 + tx4] = o4;
    }
}

// ---------------- kv projection GEMM, T2-swizzled + counted-vmcnt 2-buffer -
// grid (16 m, 8 n, 2 z): x-fastest order -> consecutive blocks share the
// B-panel (wkvT n-slice) for L2 locality.
__global__ __launch_bounds__(256) void gemm_kv(
    const unsigned short* __restrict__ A,     // cn [2048,768] bf16
    const unsigned short* __restrict__ Bt,    // wkvT [2][1024,768] bf16
    const float* __restrict__ bk, const float* __restrict__ bv,
    float* __restrict__ Ck,                   // k out [2048,1024] f32
    unsigned short* __restrict__ Cvv)         // v out [2048,1024] bf16
{
    int zi = blockIdx.z;
    const unsigned short* Bp = Bt + (long)zi * 1024 * LDIM;
    const float* bias = zi ? bv : bk;

    int m0 = blockIdx.x * 128, n0 = blockIdx.y * 128;
    int tid = threadIdx.x, lane = tid & 63, wid = tid >> 6;
    int l16 = lane & 15, quad = lane >> 4;
    int mw = (wid & 1) << 6, nw = (wid >> 1) << 6;

    __shared__ unsigned short sb[16384];

    f32x4 acc[4][4];
#pragma unroll
    for (int i = 0; i < 4; i++)
#pragma unroll
        for (int j = 0; j < 4; j++) { acc[i][j][0] = 0.f; acc[i][j][1] = 0.f; acc[i][j][2] = 0.f; acc[i][j][3] = 0.f; }

    int cg = (tid & 3) ^ ((tid >> 3) & 3);
    const unsigned short* ag = A  + (long)(m0 + (tid >> 2)) * LDIM + cg * 8;
    const unsigned short* bg = Bp + (long)(n0 + (tid >> 2)) * LDIM + cg * 8;
    const long a64 = 64L * LDIM;
    int wsl = wid * 512;
    int sw = (l16 >> 1) & 3;

    auto stage = [&](unsigned short* d, int ko) {
        gl2lds(ag + ko,        d + wsl);
        gl2lds(ag + a64 + ko,  d + wsl + 2048);
        gl2lds(bg + ko,        d + 4096 + wsl);
        gl2lds(bg + a64 + ko,  d + 4096 + wsl + 2048);
    };

    const int NT = LDIM >> 5;              // 24
    stage(sb, 0);
    stage(sb + 8192, 32);

    for (int t = 0; t < NT; ++t) {
        if (t + 1 < NT) asm volatile("s_waitcnt vmcnt(4)" ::: "memory");
        else            asm volatile("s_waitcnt vmcnt(0)" ::: "memory");
        __builtin_amdgcn_s_barrier();
        __builtin_amdgcn_sched_barrier(0);
        unsigned short* Ac = sb + (t & 1) * 8192;
        bf16x8 af[4], bfr[4];
#pragma unroll
        for (int i = 0; i < 4; i++)
            af[i] = *(const bf16x8*)&Ac[(mw + i * 16 + l16) * 32 + ((quad ^ sw) * 8)];
#pragma unroll
        for (int j = 0; j < 4; j++)
            bfr[j] = *(const bf16x8*)&Ac[4096 + (nw + j * 16 + l16) * 32 + ((quad ^ sw) * 8)];
#pragma unroll
        for (int i = 0; i < 4; i++)
#pragma unroll
            for (int j = 0; j < 4; j++)
                acc[i][j] = __builtin_amdgcn_mfma_f32_16x16x32_bf16(af[i], bfr[j], acc[i][j], 0, 0, 0);
        __builtin_amdgcn_s_barrier();
        __builtin_amdgcn_sched_barrier(0);
        if (t + 2 < NT) stage(Ac, (t + 2) << 5);
    }

#pragma unroll
    for (int j = 0; j < 4; j++) {
        int col = n0 + nw + j * 16 + l16;
        float bvv = bias[col];
#pragma unroll
        for (int i = 0; i < 4; i++) {
            int row0 = m0 + mw + i * 16 + (quad << 2);
#pragma unroll
            for (int r = 0; r < 4; r++) {
                float val = acc[i][j][r] + bvv;
                long idx = (long)(row0 + r) * DDIM + col;
                if (zi == 0) Ck[idx]  = val;
                else         Cvv[idx] = f2b(val);
            }
        }
    }
}

// ---- ctx via MFMA with inline column stats, FULL-GPU (256 blocks) ---------
// grid (8 kk-slices of 16, 32 bh). Block owns out tile [128 vv][16 kk].
__global__ __launch_bounds__(256) void ctx_mfma2s(const float* __restrict__ kraw,
    const unsigned short* __restrict__ v,
    unsigned short* __restrict__ ctxT)
{
    __shared__ unsigned short vT[128 * 72];   // 18,432 B
    __shared__ unsigned short kT[16 * 72];    //  2,304 B
    __shared__ float shm[16][17], shs[16][17];
    __shared__ float Mc[16], Sc[16];
    int kk0 = blockIdx.x * 16;      // 0..112
    int bh  = blockIdx.y;           // 0..31
    int b = bh >> 3, h = bh & 7;
    int tid = threadIdx.x, lane = tid & 63, wid = tid >> 6;
    int l16 = lane & 15, quad = lane >> 4;

    const float* kbase = kraw + (long)b * NCOND * DDIM + h * HD + kk0;

    // ---- inline per-column (max, 1/sum) over all 512 rows (16seg x 32) ----
    {
        int c = tid & 15, seg = tid >> 4;
        float m = -1e30f, s = 0.f;
#pragma unroll 4
        for (int i = 0; i < 32; i++) {
            float val = kbase[(long)(seg * 32 + i) * DDIM + c];
            float nm = fmaxf(m, val);
            s = s * __expf(m - nm) + __expf(val - nm);
            m = nm;
        }
        shm[seg][c] = m; shs[seg][c] = s;
        __syncthreads();
        if (seg == 0) {
            float M = shm[0][c], S = shs[0][c];
#pragma unroll
            for (int t = 1; t < 16; t++) {
                float m2 = shm[t][c], s2 = shs[t][c];
                float nm = fmaxf(M, m2);
                S = S * __expf(M - nm) + s2 * __expf(m2 - nm);
                M = nm;
            }
            Mc[c] = M; Sc[c] = 1.f / S;
        }
        __syncthreads();
    }

    f32x4 acc[2];
#pragma unroll
    for (int i = 0; i < 2; i++) { acc[i][0] = 0.f; acc[i][1] = 0.f; acc[i][2] = 0.f; acc[i][3] = 0.f; }

    for (int s = 0; s < 8; s++) {
        int n0 = s * 64;
        const float* kp = kbase + (long)n0 * DDIM;
        const unsigned short* vp = v + (long)b * NCOND * DDIM + (long)n0 * DDIM + h * HD;
        // kT[kk][nn]: 64n x 16kk = 1024 elems, 4 passes
#pragma unroll
        for (int p = 0; p < 4; p++) {
            int e = p * 256 + tid;
            int nn = e >> 4, kk = e & 15;
            float val = __expf(kp[(long)nn * DDIM + kk] - Mc[kk]) * Sc[kk];
            kT[kk * 72 + nn] = f2b(val);
        }
        // vT[vv][nn]: 64n x 128vv, 16 passes
#pragma unroll
        for (int p = 0; p < 16; p++) {
            int e = p * 256 + tid;
            int nn = e >> 6, v2 = (e & 63) * 2;
            unsigned int w = *(const unsigned int*)&vp[(long)nn * DDIM + v2];
            vT[v2 * 72 + nn]       = (unsigned short)w;
            vT[(v2 + 1) * 72 + nn] = (unsigned short)(w >> 16);
        }
        __syncthreads();
#pragma unroll
        for (int ks = 0; ks < 2; ks++) {
            bf16x8 af[2], bfr;
#pragma unroll
            for (int i = 0; i < 2; i++)
                af[i] = *(const bf16x8*)&vT[(wid * 32 + i * 16 + l16) * 72 + ks * 32 + quad * 8];
            bfr = *(const bf16x8*)&kT[l16 * 72 + ks * 32 + quad * 8];
#pragma unroll
            for (int i = 0; i < 2; i++)
                acc[i] = __builtin_amdgcn_mfma_f32_16x16x32_bf16(af[i], bfr, acc[i], 0, 0, 0);
        }
        __syncthreads();
    }

    unsigned short* cp = ctxT + ((long)bh << 14);
#pragma unroll
    for (int i = 0; i < 2; i++)
#pragma unroll
        for (int r = 0; r < 4; r++)
            cp[(wid * 32 + i * 16 + quad * 4 + r) * 128 + kk0 + l16] = f2b(acc[i][r]);
}

// ---------------- fused q-path: proj + bias + head-softmax + @ctx -> out ----
// UNCHANGED from round 8 (control): 1024 blocks, XCD decode, T2+T4+T5 loop.
__global__ __launch_bounds__(256, 4) void qfused(
    const unsigned short* __restrict__ xn,   // [16384,1024] bf16
    const unsigned short* __restrict__ wqT,  // [1024,1024]  bf16 (out-major)
    const float* __restrict__ bq,            // [1024]
    const unsigned short* __restrict__ ctxT, // [32][128(vv)][128(kk)] bf16
    float* __restrict__ out)                 // [16384,1024] f32
{
    __shared__ unsigned short buf[18432];        // 36,864 B
    unsigned short* Pb = buf;                    // 128*136*2 = 34,816 B (overlaps dbuf)
    float* redM = (float*)(buf + 17408);         // [2][128] at byte 34,816
    float* redS = redM + 256;                    // [2][128]

    int d = blockIdx.x;
    int xcd = d & 7, slot = d >> 3;
    int mtile = xcd * 16 + (slot >> 3);
    int head = slot & 7;
    int m0 = mtile * 128;
    int b  = m0 >> 12;
    int tid = threadIdx.x, lane = tid & 63, wid = tid >> 6;
    int l16 = lane & 15, quad = lane >> 4;
    int mw = (wid & 1) << 6, nw = (wid >> 1) << 6;
    int ch = wid >> 1;

    const unsigned short* cg2 = ctxT + ((long)(b * NHEAD + head) << 14);

    f32x4 acc[4][4];
#pragma unroll
    for (int i = 0; i < 4; i++)
#pragma unroll
        for (int j = 0; j < 4; j++) { acc[i][j][0] = 0.f; acc[i][j][1] = 0.f; acc[i][j][2] = 0.f; acc[i][j][3] = 0.f; }

    int cgs = (tid & 3) ^ ((tid >> 3) & 3);
    const unsigned short* ag = xn  + (long)(m0 + (tid >> 2)) * DDIM + cgs * 8;
    const unsigned short* bg = wqT + (long)(head * 128 + (tid >> 2)) * DDIM + cgs * 8;
    const long a64 = 64L * DDIM;
    int wsl = wid * 512;
    int sw = (l16 >> 1) & 3;

    auto stage = [&](unsigned short* dst, int ko) {
        gl2lds(ag + ko,        dst + wsl);
        gl2lds(ag + a64 + ko,  dst + wsl + 2048);
        gl2lds(bg + ko,        dst + 4096 + wsl);
        gl2lds(bg + a64 + ko,  dst + 4096 + wsl + 2048);
    };

    const int NT = DDIM >> 5;   // 32
    stage(buf, 0);
    stage(buf + 8192, 32);

    for (int t = 0; t < NT; ++t) {
        if (t + 1 < NT) asm volatile("s_waitcnt vmcnt(4)" ::: "memory");
        else            asm volatile("s_waitcnt vmcnt(0)" ::: "memory");
        __builtin_amdgcn_s_barrier();
        __builtin_amdgcn_sched_barrier(0);
        unsigned short* Ac = buf + (t & 1) * 8192;
        bf16x8 af[4], bfr[4];
#pragma unroll
        for (int i = 0; i < 4; i++)
            af[i] = *(const bf16x8*)&Ac[(mw + i * 16 + l16) * 32 + ((quad ^ sw) * 8)];
#pragma unroll
        for (int j = 0; j < 4; j++)
            bfr[j] = *(const bf16x8*)&Ac[4096 + (nw + j * 16 + l16) * 32 + ((quad ^ sw) * 8)];
        __builtin_amdgcn_s_setprio(1);
#pragma unroll
        for (int i = 0; i < 4; i++)
#pragma unroll
            for (int j = 0; j < 4; j++)
                acc[i][j] = __builtin_amdgcn_mfma_f32_16x16x32_bf16(af[i], bfr[j], acc[i][j], 0, 0, 0);
        __builtin_amdgcn_s_setprio(0);
        __builtin_amdgcn_s_barrier();
        __builtin_amdgcn_sched_barrier(0);
        if (t + 2 < NT) stage(Ac, (t + 2) << 5);
    }

    // ---- bias ----
    float bvv[4];
#pragma unroll
    for (int j = 0; j < 4; j++) bvv[j] = bq[head * 128 + nw + j * 16 + l16];
#pragma unroll
    for (int i = 0; i < 4; i++)
#pragma unroll
        for (int j = 0; j < 4; j++)
#pragma unroll
            for (int r = 0; r < 4; r++) acc[i][j][r] += bvv[j];

    // ---- row max (this wave's 64-col half) ----
    float mx[4][4];
#pragma unroll
    for (int i = 0; i < 4; i++)
#pragma unroll
        for (int r = 0; r < 4; r++) {
            float m = acc[i][0][r];
            m = fmaxf(m, acc[i][1][r]);
            m = fmaxf(m, acc[i][2][r]);
            m = fmaxf(m, acc[i][3][r]);
            mx[i][r] = m;
        }
#pragma unroll
    for (int off = 1; off < 16; off <<= 1)
#pragma unroll
        for (int i = 0; i < 4; i++)
#pragma unroll
            for (int r = 0; r < 4; r++)
                mx[i][r] = fmaxf(mx[i][r], __shfl_xor(mx[i][r], off, 64));
    if (l16 == 0) {
#pragma unroll
        for (int i = 0; i < 4; i++)
#pragma unroll
            for (int r = 0; r < 4; r++)
                redM[ch * 128 + mw + i * 16 + quad * 4 + r] = mx[i][r];
    }
    __syncthreads();

    // ---- exp (bf16-rounded), partial sums, write P to LDS ----
    float sm[4][4];
#pragma unroll
    for (int i = 0; i < 4; i++)
#pragma unroll
        for (int r = 0; r < 4; r++) {
            int row = mw + i * 16 + quad * 4 + r;
            float M = fmaxf(redM[row], redM[128 + row]);
            float s = 0.f;
#pragma unroll
            for (int j = 0; j < 4; j++) {
                unsigned short eb = f2b(__expf(acc[i][j][r] - M));
                Pb[row * 136 + nw + j * 16 + l16] = eb;
                s += b2f(eb);
            }
            sm[i][r] = s;
        }
#pragma unroll
    for (int off = 1; off < 16; off <<= 1)
#pragma unroll
        for (int i = 0; i < 4; i++)
#pragma unroll
            for (int r = 0; r < 4; r++)
                sm[i][r] += __shfl_xor(sm[i][r], off, 64);
    if (l16 == 0) {
#pragma unroll
        for (int i = 0; i < 4; i++)
#pragma unroll
            for (int r = 0; r < 4; r++)
                redS[ch * 128 + mw + i * 16 + quad * 4 + r] = sm[i][r];
    }
    __syncthreads();

    // ---- stage 2: y = P @ ctx^T (K=128), ctx fragments from global (L2) ----
    f32x4 acc2[4][4];
#pragma unroll
    for (int i = 0; i < 4; i++)
#pragma unroll
        for (int j = 0; j < 4; j++) { acc2[i][j][0] = 0.f; acc2[i][j][1] = 0.f; acc2[i][j][2] = 0.f; acc2[i][j][3] = 0.f; }
#pragma unroll
    for (int ks = 0; ks < 4; ks++) {
        bf16x8 af[4], bfr[4];
#pragma unroll
        for (int j = 0; j < 4; j++)
            bfr[j] = *(const bf16x8*)&cg2[(nw + j * 16 + l16) * 128 + ks * 32 + quad * 8];
#pragma unroll
        for (int i = 0; i < 4; i++)
            af[i] = *(const bf16x8*)&Pb[(mw + i * 16 + l16) * 136 + ks * 32 + quad * 8];
#pragma unroll
        for (int i = 0; i < 4; i++)
#pragma unroll
            for (int j = 0; j < 4; j++)
                acc2[i][j] = __builtin_amdgcn_mfma_f32_16x16x32_bf16(af[i], bfr[j], acc2[i][j], 0, 0, 0);
    }

    // ---- epilogue: scale by 1/rowsum, write f32 ----
#pragma unroll
    for (int i = 0; i < 4; i++)
#pragma unroll
        for (int r = 0; r < 4; r++) {
            int row = mw + i * 16 + quad * 4 + r;
            float invd = 1.f / (redS[row] + redS[128 + row]);
            float* op = out + (long)(m0 + row) * DDIM + head * 128;
#pragma unroll
            for (int j = 0; j < 4; j++)
                op[nw + j * 16 + l16] = acc2[i][j][r] * invd;
        }
}

extern "C" void kernel_launch(void* const* d_in, const int* in_sizes, int n_in,
                              void* d_out, int out_size, void* d_ws, size_t ws_size,
                              hipStream_t stream) {
    (void)in_sizes; (void)n_in; (void)out_size; (void)ws_size;
    const float* x     = (const float*)d_in[0];
    const float* cond  = (const float*)d_in[1];
    const float* ln_g  = (const float*)d_in[2];
    const float* ln_b  = (const float*)d_in[3];
    const float* tln_g = (const float*)d_in[4];
    const float* tln_b = (const float*)d_in[5];
    const float* Wq    = (const float*)d_in[6];
    const float* bq    = (const float*)d_in[7];
    const float* Wk    = (const float*)d_in[8];
    const float* bk    = (const float*)d_in[9];
    const float* Wv    = (const float*)d_in[10];
    const float* bv    = (const float*)d_in[11];
    float* out = (float*)d_out;

    uint8_t* w8 = (uint8_t*)d_ws;
    unsigned short* xn   = (unsigned short*)w8;                  // 33,554,432 B
    unsigned short* cn   = (unsigned short*)(w8 + 33554432);     //  3,145,728
    unsigned short* wqT  = (unsigned short*)(w8 + 36700160);     //  2,097,152
    unsigned short* wkvT = (unsigned short*)(w8 + 38797312);     //  3,145,728
    float*          fk   = (float*)(w8 + 41943040);              //  8,388,608 (raw k f32)
    unsigned short* fvb  = (unsigned short*)(w8 + 50331648);     //  4,194,304 (v bf16)
    unsigned short* ctxT = (unsigned short*)(w8 + 56623104);     //  1,048,576

    // 1) LN(x), LN(cond), W^T x3 (vectorized 64x64 tiles)
    prep<<<5248, 256, 0, stream>>>(x, ln_g, ln_b, cond, tln_g, tln_b,
                                   Wq, Wk, Wv, xn, cn, wqT, wkvT);
    // 2) k (f32) and v (bf16); consecutive blocks share B-panel
    gemm_kv<<<dim3(16, 8, 2), 256, 0, stream>>>(cn, wkvT, bk, bv, fk, fvb);
    // 3) ctx = softmax(k)^T v via MFMA, stats inlined, 256 blocks
    ctx_mfma2s<<<dim3(8, 32), 256, 0, stream>>>(fk, fvb, ctxT);
    // 4) fused q-proj + softmax + @ctx
    qfused<<<1024, 256, 0, stream>>>(xn, wqT, bq, ctxT, out);
}

// Round 10
// 243.107 us; speedup vs baseline: 1.0832x; 1.0832x over previous
//
#include <hip/hip_runtime.h>
#include <hip/hip_bf16.h>
#include <stdint.h>

#define BATCH 4
#define TLEN  4096
#define DDIM  1024
#define NCOND 512
#define LDIM  768
#define NHEAD 8
#define HD    128

typedef __bf16 bf16x8 __attribute__((ext_vector_type(8)));
typedef float  f32x4  __attribute__((ext_vector_type(4)));

__device__ __forceinline__ unsigned short f2b(float f) {
    unsigned int u = __builtin_bit_cast(unsigned int, f);
    unsigned int r = (u + 0x7fffu + ((u >> 16) & 1u)) >> 16;
    return (unsigned short)r;
}
__device__ __forceinline__ float b2f(unsigned short s) {
    unsigned int u = ((unsigned int)s) << 16;
    return __builtin_bit_cast(float, u);
}

__device__ __forceinline__ void gl2lds(const void* g, void* l) {
    __builtin_amdgcn_global_load_lds(
        (const __attribute__((address_space(1))) void*)(uintptr_t)g,
        (__attribute__((address_space(3))) void*)(uintptr_t)l,
        16, 0, 0);
}

// ---------------- LN row body: one wave per row ----------------
template<int NCH>
__device__ __forceinline__ void ln_row(const float* __restrict__ x,
    const float* __restrict__ g, const float* __restrict__ bb,
    unsigned short* __restrict__ o, long r, int lane)
{
    const int rowlen = NCH * 256;
    const float* p = x + r * (long)rowlen;
    float4 v[NCH];
    float s = 0.f, ss = 0.f;
#pragma unroll
    for (int i = 0; i < NCH; i++) {
        v[i] = *(const float4*)(p + i * 256 + lane * 4);
        s  += v[i].x + v[i].y + v[i].z + v[i].w;
        ss += v[i].x * v[i].x + v[i].y * v[i].y + v[i].z * v[i].z + v[i].w * v[i].w;
    }
#pragma unroll
    for (int off = 32; off; off >>= 1) {
        s  += __shfl_xor(s,  off, 64);
        ss += __shfl_xor(ss, off, 64);
    }
    float mu = s / rowlen;
    float rs = rsqrtf(fmaxf(ss / rowlen - mu * mu, 0.f) + 1e-5f);
    unsigned short* po = o + r * (long)rowlen;
#pragma unroll
    for (int i = 0; i < NCH; i++) {
        int c = i * 256 + lane * 4;
        float4 gv = *(const float4*)(g + c);
        float4 bv = *(const float4*)(bb + c);
        ushort4 o4;
        o4.x = f2b((v[i].x - mu) * rs * gv.x + bv.x);
        o4.y = f2b((v[i].y - mu) * rs * gv.y + bv.y);
        o4.z = f2b((v[i].z - mu) * rs * gv.z + bv.z);
        o4.w = f2b((v[i].w - mu) * rs * gv.w + bv.w);
        *(ushort4*)(po + c) = o4;
    }
}

// ---------------- prep: ln(x), ln(cond), 3x wtrans in ONE launch ----------
__global__ __launch_bounds__(256) void prep(
    const float* __restrict__ x, const float* __restrict__ ln_g,
    const float* __restrict__ ln_b,
    const float* __restrict__ cond, const float* __restrict__ tln_g,
    const float* __restrict__ tln_b,
    const float* __restrict__ Wq, const float* __restrict__ Wk,
    const float* __restrict__ Wv,
    unsigned short* __restrict__ xn, unsigned short* __restrict__ cn,
    unsigned short* __restrict__ wqT, unsigned short* __restrict__ wkvT)
{
    int blk = blockIdx.x;
    int tid = threadIdx.x, wid = tid >> 6, lane = tid & 63;
    if (blk < 4096) {
        ln_row<4>(x, ln_g, ln_b, xn, (long)blk * 4 + wid, lane);
        return;
    }
    if (blk < 4608) {
        ln_row<3>(cond, tln_g, tln_b, cn, (long)(blk - 4096) * 4 + wid, lane);
        return;
    }
    int w = blk - 4608;                 // 0..2559
    const float* W; unsigned short* Wt; int K, wi;
    if (w < 1024)      { W = Wq; Wt = wqT;               K = DDIM; wi = w; }
    else if (w < 1792) { W = Wk; Wt = wkvT;              K = LDIM; wi = w - 1024; }
    else               { W = Wv; Wt = wkvT + 768 * 1024; K = LDIM; wi = w - 1792; }
    int n0 = (wi & 31) * 32, k0 = (wi >> 5) * 32;
    __shared__ float t[32][33];
    int tx = tid & 31, ty = tid >> 5;
#pragma unroll
    for (int i = 0; i < 4; i++)
        t[ty + i * 8][tx] = W[(long)(k0 + ty + i * 8) * DDIM + n0 + tx];
    __syncthreads();
#pragma unroll
    for (int i = 0; i < 4; i++)
        Wt[(long)(n0 + ty + i * 8) * K + k0 + tx] = f2b(t[tx][ty + i * 8]);
}

// ---------------- kv projection GEMM, T2-swizzled + counted-vmcnt 2-buffer -
__global__ __launch_bounds__(256) void gemm_kv(
    const unsigned short* __restrict__ A,     // cn [2048,768] bf16
    const unsigned short* __restrict__ Bt,    // wkvT [2][1024,768] bf16
    const float* __restrict__ bk, const float* __restrict__ bv,
    float* __restrict__ Ck,                   // k out [2048,1024] f32
    unsigned short* __restrict__ Cvv)         // v out [2048,1024] bf16
{
    int zi = blockIdx.z;
    const unsigned short* Bp = Bt + (long)zi * 1024 * LDIM;
    const float* bias = zi ? bv : bk;

    int m0 = blockIdx.y * 128, n0 = blockIdx.x * 128;
    int tid = threadIdx.x, lane = tid & 63, wid = tid >> 6;
    int l16 = lane & 15, quad = lane >> 4;
    int mw = (wid & 1) << 6, nw = (wid >> 1) << 6;

    __shared__ unsigned short sb[16384];

    f32x4 acc[4][4];
#pragma unroll
    for (int i = 0; i < 4; i++)
#pragma unroll
        for (int j = 0; j < 4; j++) { acc[i][j][0] = 0.f; acc[i][j][1] = 0.f; acc[i][j][2] = 0.f; acc[i][j][3] = 0.f; }

    int cg = (tid & 3) ^ ((tid >> 3) & 3);
    const unsigned short* ag = A  + (long)(m0 + (tid >> 2)) * LDIM + cg * 8;
    const unsigned short* bg = Bp + (long)(n0 + (tid >> 2)) * LDIM + cg * 8;
    const long a64 = 64L * LDIM;
    int wsl = wid * 512;
    int sw = (l16 >> 1) & 3;

    auto stage = [&](unsigned short* d, int ko) {
        gl2lds(ag + ko,        d + wsl);
        gl2lds(ag + a64 + ko,  d + wsl + 2048);
        gl2lds(bg + ko,        d + 4096 + wsl);
        gl2lds(bg + a64 + ko,  d + 4096 + wsl + 2048);
    };

    const int NT = LDIM >> 5;              // 24
    stage(sb, 0);
    stage(sb + 8192, 32);

    for (int t = 0; t < NT; ++t) {
        if (t + 1 < NT) asm volatile("s_waitcnt vmcnt(4)" ::: "memory");
        else            asm volatile("s_waitcnt vmcnt(0)" ::: "memory");
        __builtin_amdgcn_s_barrier();
        __builtin_amdgcn_sched_barrier(0);
        unsigned short* Ac = sb + (t & 1) * 8192;
        bf16x8 af[4], bfr[4];
#pragma unroll
        for (int i = 0; i < 4; i++)
            af[i] = *(const bf16x8*)&Ac[(mw + i * 16 + l16) * 32 + ((quad ^ sw) * 8)];
#pragma unroll
        for (int j = 0; j < 4; j++)
            bfr[j] = *(const bf16x8*)&Ac[4096 + (nw + j * 16 + l16) * 32 + ((quad ^ sw) * 8)];
#pragma unroll
        for (int i = 0; i < 4; i++)
#pragma unroll
            for (int j = 0; j < 4; j++)
                acc[i][j] = __builtin_amdgcn_mfma_f32_16x16x32_bf16(af[i], bfr[j], acc[i][j], 0, 0, 0);
        __builtin_amdgcn_s_barrier();
        __builtin_amdgcn_sched_barrier(0);
        if (t + 2 < NT) stage(Ac, (t + 2) << 5);
    }

#pragma unroll
    for (int j = 0; j < 4; j++) {
        int col = n0 + nw + j * 16 + l16;
        float bvv = bias[col];
#pragma unroll
        for (int i = 0; i < 4; i++) {
            int row0 = m0 + mw + i * 16 + (quad << 2);
#pragma unroll
            for (int r = 0; r < 4; r++) {
                float val = acc[i][j][r] + bvv;
                long idx = (long)(row0 + r) * DDIM + col;
                if (zi == 0) Ck[idx]  = val;
                else         Cvv[idx] = f2b(val);
            }
        }
    }
}

// ---- ctx via MFMA with INLINE column stats (kstats fused in) --------------
// grid (4 kk-quarters, 32 bh). Block's 32 columns are disjoint from all other
// blocks' -> stats computed locally. Slice re-read is L2-hot.
__global__ __launch_bounds__(256) void ctx_mfma2s(const float* __restrict__ kraw,
    const unsigned short* __restrict__ v,
    unsigned short* __restrict__ ctxT)
{
    __shared__ unsigned short vT[128 * 72];   // 18,432 B
    __shared__ unsigned short kT[32 * 72];    //  4,608 B
    __shared__ float shm[8][33], shs[8][33];  //  4,224 B
    __shared__ float Mc[32], Sc[32];          //    256 B
    int kk0 = blockIdx.x * 32;      // 0,32,64,96
    int bh  = blockIdx.y;           // 0..31
    int b = bh >> 3, h = bh & 7;
    int tid = threadIdx.x, lane = tid & 63, wid = tid >> 6;
    int l16 = lane & 15, quad = lane >> 4;

    const float* kbase = kraw + (long)b * NCOND * DDIM + h * HD + kk0;

    // ---- inline per-column (max, 1/sum) over all 512 rows ----
    {
        int c = tid & 31, seg = tid >> 5;     // 8 segs x 64 rows
        float m = -1e30f, s = 0.f;
#pragma unroll 4
        for (int i = 0; i < 64; i++) {
            float val = kbase[(long)(seg * 64 + i) * DDIM + c];
            float nm = fmaxf(m, val);
            s = s * __expf(m - nm) + __expf(val - nm);
            m = nm;
        }
        shm[seg][c] = m; shs[seg][c] = s;
        __syncthreads();
        if (seg == 0) {
            float M = shm[0][c], S = shs[0][c];
#pragma unroll
            for (int t = 1; t < 8; t++) {
                float m2 = shm[t][c], s2 = shs[t][c];
                float nm = fmaxf(M, m2);
                S = S * __expf(M - nm) + s2 * __expf(m2 - nm);
                M = nm;
            }
            Mc[c] = M; Sc[c] = 1.f / S;
        }
        __syncthreads();
    }

    f32x4 acc[2][2];
#pragma unroll
    for (int i = 0; i < 2; i++)
#pragma unroll
        for (int j = 0; j < 2; j++) { acc[i][j][0] = 0.f; acc[i][j][1] = 0.f; acc[i][j][2] = 0.f; acc[i][j][3] = 0.f; }

    for (int s = 0; s < 8; s++) {
        int n0 = s * 64;
        const float* kp = kbase + (long)n0 * DDIM;
        const unsigned short* vp = v + (long)b * NCOND * DDIM + (long)n0 * DDIM + h * HD;
#pragma unroll
        for (int p = 0; p < 8; p++) {
            int e = p * 256 + tid;
            int nn = e >> 5, kk = e & 31;
            float val = __expf(kp[(long)nn * DDIM + kk] - Mc[kk]) * Sc[kk];
            kT[kk * 72 + nn] = f2b(val);
        }
#pragma unroll
        for (int p = 0; p < 16; p++) {
            int e = p * 256 + tid;
            int nn = e >> 6, v2 = (e & 63) * 2;
            unsigned int w = *(const unsigned int*)&vp[(long)nn * DDIM + v2];
            vT[v2 * 72 + nn]       = (unsigned short)w;
            vT[(v2 + 1) * 72 + nn] = (unsigned short)(w >> 16);
        }
        __syncthreads();
#pragma unroll
        for (int ks = 0; ks < 2; ks++) {
            bf16x8 af[2], bfr[2];
#pragma unroll
            for (int i = 0; i < 2; i++)
                af[i] = *(const bf16x8*)&vT[(wid * 32 + i * 16 + l16) * 72 + ks * 32 + quad * 8];
#pragma unroll
            for (int j = 0; j < 2; j++)
                bfr[j] = *(const bf16x8*)&kT[(j * 16 + l16) * 72 + ks * 32 + quad * 8];
#pragma unroll
            for (int i = 0; i < 2; i++)
#pragma unroll
                for (int j = 0; j < 2; j++)
                    acc[i][j] = __builtin_amdgcn_mfma_f32_16x16x32_bf16(af[i], bfr[j], acc[i][j], 0, 0, 0);
        }
        __syncthreads();
    }

    unsigned short* cp = ctxT + ((long)bh << 14);
#pragma unroll
    for (int i = 0; i < 2; i++)
#pragma unroll
        for (int j = 0; j < 2; j++)
#pragma unroll
            for (int r = 0; r < 4; r++)
                cp[(wid * 32 + i * 16 + quad * 4 + r) * 128 + kk0 + j * 16 + l16] =
                    f2b(acc[i][j][r]);
}

// ---------------- fused q-path: proj + bias + head-softmax + @ctx -> out ----
// 1024 blocks, XCD decode: 8 consecutive same-XCD blocks share an mtile.
// T2 swizzle + T4 counted-vmcnt + T5 setprio in the K-loop.
__global__ __launch_bounds__(256, 4) void qfused(
    const unsigned short* __restrict__ xn,   // [16384,1024] bf16
    const unsigned short* __restrict__ wqT,  // [1024,1024]  bf16 (out-major)
    const float* __restrict__ bq,            // [1024]
    const unsigned short* __restrict__ ctxT, // [32][128(vv)][128(kk)] bf16
    float* __restrict__ out)                 // [16384,1024] f32
{
    __shared__ unsigned short buf[18432];        // 36,864 B
    unsigned short* Pb = buf;                    // 128*136*2 = 34,816 B (overlaps dbuf)
    float* redM = (float*)(buf + 17408);         // [2][128] at byte 34,816
    float* redS = redM + 256;                    // [2][128]

    int d = blockIdx.x;
    int xcd = d & 7, slot = d >> 3;
    int mtile = xcd * 16 + (slot >> 3);
    int head = slot & 7;
    int m0 = mtile * 128;
    int b  = m0 >> 12;
    int tid = threadIdx.x, lane = tid & 63, wid = tid >> 6;
    int l16 = lane & 15, quad = lane >> 4;
    int mw = (wid & 1) << 6, nw = (wid >> 1) << 6;
    int ch = wid >> 1;

    const unsigned short* cg2 = ctxT + ((long)(b * NHEAD + head) << 14);

    f32x4 acc[4][4];
#pragma unroll
    for (int i = 0; i < 4; i++)
#pragma unroll
        for (int j = 0; j < 4; j++) { acc[i][j][0] = 0.f; acc[i][j][1] = 0.f; acc[i][j][2] = 0.f; acc[i][j][3] = 0.f; }

    int cgs = (tid & 3) ^ ((tid >> 3) & 3);
    const unsigned short* ag = xn  + (long)(m0 + (tid >> 2)) * DDIM + cgs * 8;
    const unsigned short* bg = wqT + (long)(head * 128 + (tid >> 2)) * DDIM + cgs * 8;
    const long a64 = 64L * DDIM;
    int wsl = wid * 512;
    int sw = (l16 >> 1) & 3;

    auto stage = [&](unsigned short* dst, int ko) {
        gl2lds(ag + ko,        dst + wsl);
        gl2lds(ag + a64 + ko,  dst + wsl + 2048);
        gl2lds(bg + ko,        dst + 4096 + wsl);
        gl2lds(bg + a64 + ko,  dst + 4096 + wsl + 2048);
    };

    const int NT = DDIM >> 5;   // 32
    stage(buf, 0);
    stage(buf + 8192, 32);

    for (int t = 0; t < NT; ++t) {
        if (t + 1 < NT) asm volatile("s_waitcnt vmcnt(4)" ::: "memory");
        else            asm volatile("s_waitcnt vmcnt(0)" ::: "memory");
        __builtin_amdgcn_s_barrier();
        __builtin_amdgcn_sched_barrier(0);
        unsigned short* Ac = buf + (t & 1) * 8192;
        bf16x8 af[4], bfr[4];
#pragma unroll
        for (int i = 0; i < 4; i++)
            af[i] = *(const bf16x8*)&Ac[(mw + i * 16 + l16) * 32 + ((quad ^ sw) * 8)];
#pragma unroll
        for (int j = 0; j < 4; j++)
            bfr[j] = *(const bf16x8*)&Ac[4096 + (nw + j * 16 + l16) * 32 + ((quad ^ sw) * 8)];
        __builtin_amdgcn_s_setprio(1);
#pragma unroll
        for (int i = 0; i < 4; i++)
#pragma unroll
            for (int j = 0; j < 4; j++)
                acc[i][j] = __builtin_amdgcn_mfma_f32_16x16x32_bf16(af[i], bfr[j], acc[i][j], 0, 0, 0);
        __builtin_amdgcn_s_setprio(0);
        __builtin_amdgcn_s_barrier();
        __builtin_amdgcn_sched_barrier(0);
        if (t + 2 < NT) stage(Ac, (t + 2) << 5);
    }

    // ---- bias ----
    float bvv[4];
#pragma unroll
    for (int j = 0; j < 4; j++) bvv[j] = bq[head * 128 + nw + j * 16 + l16];
#pragma unroll
    for (int i = 0; i < 4; i++)
#pragma unroll
        for (int j = 0; j < 4; j++)
#pragma unroll
            for (int r = 0; r < 4; r++) acc[i][j][r] += bvv[j];

    // ---- row max (this wave's 64-col half) ----
    float mx[4][4];
#pragma unroll
    for (int i = 0; i < 4; i++)
#pragma unroll
        for (int r = 0; r < 4; r++) {
            float m = acc[i][0][r];
            m = fmaxf(m, acc[i][1][r]);
            m = fmaxf(m, acc[i][2][r]);
            m = fmaxf(m, acc[i][3][r]);
            mx[i][r] = m;
        }
#pragma unroll
    for (int off = 1; off < 16; off <<= 1)
#pragma unroll
        for (int i = 0; i < 4; i++)
#pragma unroll
            for (int r = 0; r < 4; r++)
                mx[i][r] = fmaxf(mx[i][r], __shfl_xor(mx[i][r], off, 64));
    if (l16 == 0) {
#pragma unroll
        for (int i = 0; i < 4; i++)
#pragma unroll
            for (int r = 0; r < 4; r++)
                redM[ch * 128 + mw + i * 16 + quad * 4 + r] = mx[i][r];
    }
    __syncthreads();

    // ---- exp (bf16-rounded), partial sums, write P to LDS ----
    float sm[4][4];
#pragma unroll
    for (int i = 0; i < 4; i++)
#pragma unroll
        for (int r = 0; r < 4; r++) {
            int row = mw + i * 16 + quad * 4 + r;
            float M = fmaxf(redM[row], redM[128 + row]);
            float s = 0.f;
#pragma unroll
            for (int j = 0; j < 4; j++) {
                unsigned short eb = f2b(__expf(acc[i][j][r] - M));
                Pb[row * 136 + nw + j * 16 + l16] = eb;
                s += b2f(eb);
            }
            sm[i][r] = s;
        }
#pragma unroll
    for (int off = 1; off < 16; off <<= 1)
#pragma unroll
        for (int i = 0; i < 4; i++)
#pragma unroll
            for (int r = 0; r < 4; r++)
                sm[i][r] += __shfl_xor(sm[i][r], off, 64);
    if (l16 == 0) {
#pragma unroll
        for (int i = 0; i < 4; i++)
#pragma unroll
            for (int r = 0; r < 4; r++)
                redS[ch * 128 + mw + i * 16 + quad * 4 + r] = sm[i][r];
    }
    __syncthreads();

    // ---- stage 2: y = P @ ctx^T (K=128), ctx fragments from global (L2) ----
    f32x4 acc2[4][4];
#pragma unroll
    for (int i = 0; i < 4; i++)
#pragma unroll
        for (int j = 0; j < 4; j++) { acc2[i][j][0] = 0.f; acc2[i][j][1] = 0.f; acc2[i][j][2] = 0.f; acc2[i][j][3] = 0.f; }
#pragma unroll
    for (int ks = 0; ks < 4; ks++) {
        bf16x8 af[4], bfr[4];
#pragma unroll
        for (int j = 0; j < 4; j++)
            bfr[j] = *(const bf16x8*)&cg2[(nw + j * 16 + l16) * 128 + ks * 32 + quad * 8];
#pragma unroll
        for (int i = 0; i < 4; i++)
            af[i] = *(const bf16x8*)&Pb[(mw + i * 16 + l16) * 136 + ks * 32 + quad * 8];
#pragma unroll
        for (int i = 0; i < 4; i++)
#pragma unroll
            for (int j = 0; j < 4; j++)
                acc2[i][j] = __builtin_amdgcn_mfma_f32_16x16x32_bf16(af[i], bfr[j], acc2[i][j], 0, 0, 0);
    }

    // ---- epilogue: scale by 1/rowsum, write f32 ----
#pragma unroll
    for (int i = 0; i < 4; i++)
#pragma unroll
        for (int r = 0; r < 4; r++) {
            int row = mw + i * 16 + quad * 4 + r;
            float invd = 1.f / (redS[row] + redS[128 + row]);
            float* op = out + (long)(m0 + row) * DDIM + head * 128;
#pragma unroll
            for (int j = 0; j < 4; j++)
                op[nw + j * 16 + l16] = acc2[i][j][r] * invd;
        }
}

extern "C" void kernel_launch(void* const* d_in, const int* in_sizes, int n_in,
                              void* d_out, int out_size, void* d_ws, size_t ws_size,
                              hipStream_t stream) {
    (void)in_sizes; (void)n_in; (void)out_size; (void)ws_size;
    const float* x     = (const float*)d_in[0];
    const float* cond  = (const float*)d_in[1];
    const float* ln_g  = (const float*)d_in[2];
    const float* ln_b  = (const float*)d_in[3];
    const float* tln_g = (const float*)d_in[4];
    const float* tln_b = (const float*)d_in[5];
    const float* Wq    = (const float*)d_in[6];
    const float* bq    = (const float*)d_in[7];
    const float* Wk    = (const float*)d_in[8];
    const float* bk    = (const float*)d_in[9];
    const float* Wv    = (const float*)d_in[10];
    const float* bv    = (const float*)d_in[11];
    float* out = (float*)d_out;

    uint8_t* w8 = (uint8_t*)d_ws;
    unsigned short* xn   = (unsigned short*)w8;                  // 33,554,432 B
    unsigned short* cn   = (unsigned short*)(w8 + 33554432);     //  3,145,728
    unsigned short* wqT  = (unsigned short*)(w8 + 36700160);     //  2,097,152
    unsigned short* wkvT = (unsigned short*)(w8 + 38797312);     //  3,145,728
    float*          fk   = (float*)(w8 + 41943040);              //  8,388,608 (raw k f32)
    unsigned short* fvb  = (unsigned short*)(w8 + 50331648);     //  4,194,304 (v bf16)
    unsigned short* ctxT = (unsigned short*)(w8 + 56623104);     //  1,048,576

    // 1) LN(x), LN(cond), W^T x3
    prep<<<7168, 256, 0, stream>>>(x, ln_g, ln_b, cond, tln_g, tln_b,
                                   Wq, Wk, Wv, xn, cn, wqT, wkvT);
    // 2) k (f32) and v (bf16)
    gemm_kv<<<dim3(8, 16, 2), 256, 0, stream>>>(cn, wkvT, bk, bv, fk, fvb);
    // 3) ctx = softmax(k)^T v via MFMA, stats inlined, bf16 out
    ctx_mfma2s<<<dim3(4, 32), 256, 0, stream>>>(fk, fvb, ctxT);
    // 4) fused q-proj + softmax + @ctx
    qfused<<<1024, 256, 0, stream>>>(xn, wqT, bq, ctxT, out);
}

// Round 11
// 229.423 us; speedup vs baseline: 1.1478x; 1.0596x over previous
//
#include <hip/hip_runtime.h>
#include <hip/hip_bf16.h>
#include <stdint.h>

#define BATCH 4
#define TLEN  4096
#define DDIM  1024
#define NCOND 512
#define LDIM  768
#define NHEAD 8
#define HD    128

typedef __bf16 bf16x8 __attribute__((ext_vector_type(8)));
typedef float  f32x4  __attribute__((ext_vector_type(4)));

__device__ __forceinline__ unsigned short f2b(float f) {
    unsigned int u = __builtin_bit_cast(unsigned int, f);
    unsigned int r = (u + 0x7fffu + ((u >> 16) & 1u)) >> 16;
    return (unsigned short)r;
}
__device__ __forceinline__ float b2f(unsigned short s) {
    unsigned int u = ((unsigned int)s) << 16;
    return __builtin_bit_cast(float, u);
}

__device__ __forceinline__ void gl2lds(const void* g, void* l) {
    __builtin_amdgcn_global_load_lds(
        (const __attribute__((address_space(1))) void*)(uintptr_t)g,
        (__attribute__((address_space(3))) void*)(uintptr_t)l,
        16, 0, 0);
}

// ---------------- LN row body: one wave per row ----------------
template<int NCH>
__device__ __forceinline__ void ln_row(const float* __restrict__ x,
    const float* __restrict__ g, const float* __restrict__ bb,
    unsigned short* __restrict__ o, long r, int lane)
{
    const int rowlen = NCH * 256;
    const float* p = x + r * (long)rowlen;
    float4 v[NCH];
    float s = 0.f, ss = 0.f;
#pragma unroll
    for (int i = 0; i < NCH; i++) {
        v[i] = *(const float4*)(p + i * 256 + lane * 4);
        s  += v[i].x + v[i].y + v[i].z + v[i].w;
        ss += v[i].x * v[i].x + v[i].y * v[i].y + v[i].z * v[i].z + v[i].w * v[i].w;
    }
#pragma unroll
    for (int off = 32; off; off >>= 1) {
        s  += __shfl_xor(s,  off, 64);
        ss += __shfl_xor(ss, off, 64);
    }
    float mu = s / rowlen;
    float rs = rsqrtf(fmaxf(ss / rowlen - mu * mu, 0.f) + 1e-5f);
    unsigned short* po = o + r * (long)rowlen;
#pragma unroll
    for (int i = 0; i < NCH; i++) {
        int c = i * 256 + lane * 4;
        float4 gv = *(const float4*)(g + c);
        float4 bv = *(const float4*)(bb + c);
        ushort4 o4;
        o4.x = f2b((v[i].x - mu) * rs * gv.x + bv.x);
        o4.y = f2b((v[i].y - mu) * rs * gv.y + bv.y);
        o4.z = f2b((v[i].z - mu) * rs * gv.z + bv.z);
        o4.w = f2b((v[i].w - mu) * rs * gv.w + bv.w);
        *(ushort4*)(po + c) = o4;
    }
}

// ---------------- prep: ln(x), ln(cond), 3x wtrans in ONE launch ----------
__global__ __launch_bounds__(256) void prep(
    const float* __restrict__ x, const float* __restrict__ ln_g,
    const float* __restrict__ ln_b,
    const float* __restrict__ cond, const float* __restrict__ tln_g,
    const float* __restrict__ tln_b,
    const float* __restrict__ Wq, const float* __restrict__ Wk,
    const float* __restrict__ Wv,
    unsigned short* __restrict__ xn, unsigned short* __restrict__ cn,
    unsigned short* __restrict__ wqT, unsigned short* __restrict__ wkvT)
{
    int blk = blockIdx.x;
    int tid = threadIdx.x, wid = tid >> 6, lane = tid & 63;
    if (blk < 4096) {
        ln_row<4>(x, ln_g, ln_b, xn, (long)blk * 4 + wid, lane);
        return;
    }
    if (blk < 4608) {
        ln_row<3>(cond, tln_g, tln_b, cn, (long)(blk - 4096) * 4 + wid, lane);
        return;
    }
    int w = blk - 4608;                 // 0..2559
    const float* W; unsigned short* Wt; int K, wi;
    if (w < 1024)      { W = Wq; Wt = wqT;               K = DDIM; wi = w; }
    else if (w < 1792) { W = Wk; Wt = wkvT;              K = LDIM; wi = w - 1024; }
    else               { W = Wv; Wt = wkvT + 768 * 1024; K = LDIM; wi = w - 1792; }
    int n0 = (wi & 31) * 32, k0 = (wi >> 5) * 32;
    __shared__ float t[32][33];
    int tx = tid & 31, ty = tid >> 5;
#pragma unroll
    for (int i = 0; i < 4; i++)
        t[ty + i * 8][tx] = W[(long)(k0 + ty + i * 8) * DDIM + n0 + tx];
    __syncthreads();
#pragma unroll
    for (int i = 0; i < 4; i++)
        Wt[(long)(n0 + ty + i * 8) * K + k0 + tx] = f2b(t[tx][ty + i * 8]);
}

// ---------------- kv projection GEMM, T2-swizzled + counted-vmcnt 2-buffer -
__global__ __launch_bounds__(256) void gemm_kv(
    const unsigned short* __restrict__ A,     // cn [2048,768] bf16
    const unsigned short* __restrict__ Bt,    // wkvT [2][1024,768] bf16
    const float* __restrict__ bk, const float* __restrict__ bv,
    float* __restrict__ Ck,                   // k out [2048,1024] f32
    unsigned short* __restrict__ Cvv)         // v out [2048,1024] bf16
{
    int zi = blockIdx.z;
    const unsigned short* Bp = Bt + (long)zi * 1024 * LDIM;
    const float* bias = zi ? bv : bk;

    int m0 = blockIdx.y * 128, n0 = blockIdx.x * 128;
    int tid = threadIdx.x, lane = tid & 63, wid = tid >> 6;
    int l16 = lane & 15, quad = lane >> 4;
    int mw = (wid & 1) << 6, nw = (wid >> 1) << 6;

    __shared__ unsigned short sb[16384];

    f32x4 acc[4][4];
#pragma unroll
    for (int i = 0; i < 4; i++)
#pragma unroll
        for (int j = 0; j < 4; j++) { acc[i][j][0] = 0.f; acc[i][j][1] = 0.f; acc[i][j][2] = 0.f; acc[i][j][3] = 0.f; }

    int cg = (tid & 3) ^ ((tid >> 3) & 3);
    const unsigned short* ag = A  + (long)(m0 + (tid >> 2)) * LDIM + cg * 8;
    const unsigned short* bg = Bp + (long)(n0 + (tid >> 2)) * LDIM + cg * 8;
    const long a64 = 64L * LDIM;
    int wsl = wid * 512;
    int sw = (l16 >> 1) & 3;

    auto stage = [&](unsigned short* d, int ko) {
        gl2lds(ag + ko,        d + wsl);
        gl2lds(ag + a64 + ko,  d + wsl + 2048);
        gl2lds(bg + ko,        d + 4096 + wsl);
        gl2lds(bg + a64 + ko,  d + 4096 + wsl + 2048);
    };

    const int NT = LDIM >> 5;              // 24
    stage(sb, 0);
    stage(sb + 8192, 32);

    for (int t = 0; t < NT; ++t) {
        if (t + 1 < NT) asm volatile("s_waitcnt vmcnt(4)" ::: "memory");
        else            asm volatile("s_waitcnt vmcnt(0)" ::: "memory");
        __builtin_amdgcn_s_barrier();
        __builtin_amdgcn_sched_barrier(0);
        unsigned short* Ac = sb + (t & 1) * 8192;
        bf16x8 af[4], bfr[4];
#pragma unroll
        for (int i = 0; i < 4; i++)
            af[i] = *(const bf16x8*)&Ac[(mw + i * 16 + l16) * 32 + ((quad ^ sw) * 8)];
#pragma unroll
        for (int j = 0; j < 4; j++)
            bfr[j] = *(const bf16x8*)&Ac[4096 + (nw + j * 16 + l16) * 32 + ((quad ^ sw) * 8)];
#pragma unroll
        for (int i = 0; i < 4; i++)
#pragma unroll
            for (int j = 0; j < 4; j++)
                acc[i][j] = __builtin_amdgcn_mfma_f32_16x16x32_bf16(af[i], bfr[j], acc[i][j], 0, 0, 0);
        __builtin_amdgcn_s_barrier();
        __builtin_amdgcn_sched_barrier(0);
        if (t + 2 < NT) stage(Ac, (t + 2) << 5);
    }

#pragma unroll
    for (int j = 0; j < 4; j++) {
        int col = n0 + nw + j * 16 + l16;
        float bvv = bias[col];
#pragma unroll
        for (int i = 0; i < 4; i++) {
            int row0 = m0 + mw + i * 16 + (quad << 2);
#pragma unroll
            for (int r = 0; r < 4; r++) {
                float val = acc[i][j][r] + bvv;
                long idx = (long)(row0 + r) * DDIM + col;
                if (zi == 0) Ck[idx]  = val;
                else         Cvv[idx] = f2b(val);
            }
        }
    }
}

// ---- ctx via MFMA with INLINE column stats (kstats fused in) --------------
__global__ __launch_bounds__(256) void ctx_mfma2s(const float* __restrict__ kraw,
    const unsigned short* __restrict__ v,
    unsigned short* __restrict__ ctxT)
{
    __shared__ unsigned short vT[128 * 72];   // 18,432 B
    __shared__ unsigned short kT[32 * 72];    //  4,608 B
    __shared__ float shm[8][33], shs[8][33];  //  4,224 B
    __shared__ float Mc[32], Sc[32];          //    256 B
    int kk0 = blockIdx.x * 32;      // 0,32,64,96
    int bh  = blockIdx.y;           // 0..31
    int b = bh >> 3, h = bh & 7;
    int tid = threadIdx.x, lane = tid & 63, wid = tid >> 6;
    int l16 = lane & 15, quad = lane >> 4;

    const float* kbase = kraw + (long)b * NCOND * DDIM + h * HD + kk0;

    // ---- inline per-column (max, 1/sum) over all 512 rows ----
    {
        int c = tid & 31, seg = tid >> 5;     // 8 segs x 64 rows
        float m = -1e30f, s = 0.f;
#pragma unroll 4
        for (int i = 0; i < 64; i++) {
            float val = kbase[(long)(seg * 64 + i) * DDIM + c];
            float nm = fmaxf(m, val);
            s = s * __expf(m - nm) + __expf(val - nm);
            m = nm;
        }
        shm[seg][c] = m; shs[seg][c] = s;
        __syncthreads();
        if (seg == 0) {
            float M = shm[0][c], S = shs[0][c];
#pragma unroll
            for (int t = 1; t < 8; t++) {
                float m2 = shm[t][c], s2 = shs[t][c];
                float nm = fmaxf(M, m2);
                S = S * __expf(M - nm) + s2 * __expf(m2 - nm);
                M = nm;
            }
            Mc[c] = M; Sc[c] = 1.f / S;
        }
        __syncthreads();
    }

    f32x4 acc[2][2];
#pragma unroll
    for (int i = 0; i < 2; i++)
#pragma unroll
        for (int j = 0; j < 2; j++) { acc[i][j][0] = 0.f; acc[i][j][1] = 0.f; acc[i][j][2] = 0.f; acc[i][j][3] = 0.f; }

    for (int s = 0; s < 8; s++) {
        int n0 = s * 64;
        const float* kp = kbase + (long)n0 * DDIM;
        const unsigned short* vp = v + (long)b * NCOND * DDIM + (long)n0 * DDIM + h * HD;
#pragma unroll
        for (int p = 0; p < 8; p++) {
            int e = p * 256 + tid;
            int nn = e >> 5, kk = e & 31;
            float val = __expf(kp[(long)nn * DDIM + kk] - Mc[kk]) * Sc[kk];
            kT[kk * 72 + nn] = f2b(val);
        }
#pragma unroll
        for (int p = 0; p < 16; p++) {
            int e = p * 256 + tid;
            int nn = e >> 6, v2 = (e & 63) * 2;
            unsigned int w = *(const unsigned int*)&vp[(long)nn * DDIM + v2];
            vT[v2 * 72 + nn]       = (unsigned short)w;
            vT[(v2 + 1) * 72 + nn] = (unsigned short)(w >> 16);
        }
        __syncthreads();
#pragma unroll
        for (int ks = 0; ks < 2; ks++) {
            bf16x8 af[2], bfr[2];
#pragma unroll
            for (int i = 0; i < 2; i++)
                af[i] = *(const bf16x8*)&vT[(wid * 32 + i * 16 + l16) * 72 + ks * 32 + quad * 8];
#pragma unroll
            for (int j = 0; j < 2; j++)
                bfr[j] = *(const bf16x8*)&kT[(j * 16 + l16) * 72 + ks * 32 + quad * 8];
#pragma unroll
            for (int i = 0; i < 2; i++)
#pragma unroll
                for (int j = 0; j < 2; j++)
                    acc[i][j] = __builtin_amdgcn_mfma_f32_16x16x32_bf16(af[i], bfr[j], acc[i][j], 0, 0, 0);
        }
        __syncthreads();
    }

    unsigned short* cp = ctxT + ((long)bh << 14);
#pragma unroll
    for (int i = 0; i < 2; i++)
#pragma unroll
        for (int j = 0; j < 2; j++)
#pragma unroll
            for (int r = 0; r < 4; r++)
                cp[(wid * 32 + i * 16 + quad * 4 + r) * 128 + kk0 + j * 16 + l16] =
                    f2b(acc[i][j][r]);
}

// ---- qfused2: 256x256 tile (one head-PAIR), 512 thr / 8 waves (2Mx4N),
// per-wave 128x64 (acc 8x4) — m201 geometry. BK=64, 4 sub-phases per K-tile:
// {ds_read quadrant (8 or 4 b128; B-frags reused across m-half phases) |
//  stage 1 half-tile of t+1 | barrier | lgkmcnt(0)+sched_barrier |
//  setprio(1) 16xMFMA setprio(0) | barrier}.
// Gate per K-tile: vmcnt(0)+barrier BEFORE any same-tile issue (T4 invariant:
// never wait on loads issued this tile; gated loads have >=4 phases slack).
// 3-bit chunk-XOR swizzle (slot = chunk ^ (row&7)) -> 2-way banks.
// LDS 143,360 B: dbuf A[2]+B[2] 128K, Pb[256][264]+red overlap. 1 blk/CU.
__global__ __launch_bounds__(512, 2) void qfused2(
    const unsigned short* __restrict__ xn,   // [16384,1024] bf16
    const unsigned short* __restrict__ wqT,  // [1024,1024]  bf16 (out-major)
    const float* __restrict__ bq,            // [1024]
    const unsigned short* __restrict__ ctxT, // [32][128(vv)][128(kk)] bf16
    float* __restrict__ out)                 // [16384,1024] f32
{
    __shared__ unsigned short buf[71680];        // 143,360 B
    unsigned short* sbA = buf;                   // [2][256][64]  65,536 B
    unsigned short* sbB = buf + 32768;           // [2][256][64]  65,536 B
    unsigned short* Pb  = buf;                   // [256][264] 135,168 B (overlap)
    float* redM = (float*)(buf + 67584);         // [4][256] at byte 135,168
    float* redS = redM + 1024;                   // [4][256]

    int d = blockIdx.x;
    int swz = (d & 7) * 32 + (d >> 3);           // XCD: 4 consecutive = same mt
    int mt = swz >> 2, hp = swz & 3;
    int m0 = mt * 256;
    int b  = m0 >> 12;

    int tid = threadIdx.x, lane = tid & 63, wid = tid >> 6;
    int l16 = lane & 15, quad = lane >> 4;
    int wm = wid & 1, wn = wid >> 1;             // wave: 128 rows (wm), 64 cols (wn)
    int h  = wn >> 1;                            // local head 0/1 (cols 0-127 / 128-255)

    f32x4 acc[8][4];
#pragma unroll
    for (int i = 0; i < 8; i++)
#pragma unroll
        for (int j = 0; j < 4; j++) { acc[i][j][0] = 0.f; acc[i][j][1] = 0.f; acc[i][j][2] = 0.f; acc[i][j][3] = 0.f; }

    // staging: per gl2lds 512 thr x 16B = 64 rows x 128B. slot = chunk^(row&7)
    int cgs  = (tid & 7) ^ ((tid >> 3) & 7);
    int rsub = tid >> 3;                          // 0..63
    int ldsb = rsub * 64 + (tid & 7) * 8;         // ushort idx, linear per-wave
    const unsigned short* agb = xn  + (long)(m0 + rsub) * DDIM + cgs * 8;
    const unsigned short* bgb = wqT + (long)(hp * 256 + rsub) * DDIM + cgs * 8;

    auto stageA = [&](int t1, int hh) {
        unsigned short* dst = sbA + (t1 & 1) * 16384 + hh * 8192 + ldsb;
        const unsigned short* g = agb + (long)(hh * 128) * DDIM + t1 * 64;
        gl2lds(g, dst);
        gl2lds(g + 64L * DDIM, dst + 4096);
    };
    auto stageB = [&](int t1, int hh) {
        unsigned short* dst = sbB + (t1 & 1) * 16384 + hh * 8192 + ldsb;
        const unsigned short* g = bgb + (long)(hh * 128) * DDIM + t1 * 64;
        gl2lds(g, dst);
        gl2lds(g + 64L * DDIM, dst + 4096);
    };

    // prologue: tile 0, all 4 half-tiles
    stageA(0, 0); stageA(0, 1); stageB(0, 0); stageB(0, 1);

    int sl7 = l16 & 7;
    const int NT = DDIM >> 6;                     // 16 K-tiles of 64
    for (int t = 0; t < NT; ++t) {
        // gate: all of tile t's loads landed (issued >=4 phases ago)
        asm volatile("s_waitcnt vmcnt(0)" ::: "memory");
        __builtin_amdgcn_s_barrier();
        __builtin_amdgcn_sched_barrier(0);
        const unsigned short* A = sbA + (t & 1) * 16384;
        const unsigned short* B = sbB + (t & 1) * 16384;
        bool pf = (t + 1 < NT);
#pragma unroll
        for (int ks = 0; ks < 2; ++ks) {
            int slot = ((ks * 4 + quad) ^ sl7) * 8;
            bf16x8 bfr[4];
#pragma unroll
            for (int j = 0; j < 4; ++j)
                bfr[j] = *(const bf16x8*)&B[(wn * 64 + j * 16 + l16) * 64 + slot];
#pragma unroll
            for (int mh = 0; mh < 2; ++mh) {
                bf16x8 af[4];
#pragma unroll
                for (int ii = 0; ii < 4; ++ii)
                    af[ii] = *(const bf16x8*)&A[(wm * 128 + (mh * 4 + ii) * 16 + l16) * 64 + slot];
                if (pf) {
                    int ph = ks * 2 + mh;
                    if      (ph == 0) stageA(t + 1, 0);
                    else if (ph == 1) stageA(t + 1, 1);
                    else if (ph == 2) stageB(t + 1, 0);
                    else              stageB(t + 1, 1);
                }
                __builtin_amdgcn_s_barrier();
                asm volatile("s_waitcnt lgkmcnt(0)" ::: "memory");
                __builtin_amdgcn_sched_barrier(0);
                __builtin_amdgcn_s_setprio(1);
#pragma unroll
                for (int ii = 0; ii < 4; ++ii)
#pragma unroll
                    for (int j = 0; j < 4; ++j)
                        acc[mh * 4 + ii][j] = __builtin_amdgcn_mfma_f32_16x16x32_bf16(
                            af[ii], bfr[j], acc[mh * 4 + ii][j], 0, 0, 0);
                __builtin_amdgcn_s_setprio(0);
                __builtin_amdgcn_s_barrier();
                __builtin_amdgcn_sched_barrier(0);
            }
        }
    }

    // ---- bias ----
    float bvv[4];
#pragma unroll
    for (int j = 0; j < 4; j++) bvv[j] = bq[hp * 256 + wn * 64 + j * 16 + l16];
#pragma unroll
    for (int i = 0; i < 8; i++)
#pragma unroll
        for (int j = 0; j < 4; j++)
#pragma unroll
            for (int r = 0; r < 4; r++) acc[i][j][r] += bvv[j];

    // ---- row max over wave's 64 cols ----
    float mx[8][4];
#pragma unroll
    for (int i = 0; i < 8; i++)
#pragma unroll
        for (int r = 0; r < 4; r++) {
            float m = fmaxf(fmaxf(acc[i][0][r], acc[i][1][r]),
                            fmaxf(acc[i][2][r], acc[i][3][r]));
            mx[i][r] = m;
        }
#pragma unroll
    for (int off = 1; off < 16; off <<= 1)
#pragma unroll
        for (int i = 0; i < 8; i++)
#pragma unroll
            for (int r = 0; r < 4; r++)
                mx[i][r] = fmaxf(mx[i][r], __shfl_xor(mx[i][r], off, 64));
    if (l16 == 0) {
#pragma unroll
        for (int i = 0; i < 8; i++)
#pragma unroll
            for (int r = 0; r < 4; r++)
                redM[wn * 256 + wm * 128 + i * 16 + quad * 4 + r] = mx[i][r];
    }
    __syncthreads();

    // ---- exp (bf16-rounded), partial sums, P to LDS ----
    float sm[8][4];
#pragma unroll
    for (int i = 0; i < 8; i++)
#pragma unroll
        for (int r = 0; r < 4; r++) {
            int row = wm * 128 + i * 16 + quad * 4 + r;
            float M = fmaxf(redM[(h * 2) * 256 + row], redM[(h * 2 + 1) * 256 + row]);
            float s = 0.f;
#pragma unroll
            for (int j = 0; j < 4; j++) {
                unsigned short eb = f2b(__expf(acc[i][j][r] - M));
                Pb[row * 264 + wn * 64 + j * 16 + l16] = eb;
                s += b2f(eb);
            }
            sm[i][r] = s;
        }
#pragma unroll
    for (int off = 1; off < 16; off <<= 1)
#pragma unroll
        for (int i = 0; i < 8; i++)
#pragma unroll
            for (int r = 0; r < 4; r++)
                sm[i][r] += __shfl_xor(sm[i][r], off, 64);
    if (l16 == 0) {
#pragma unroll
        for (int i = 0; i < 8; i++)
#pragma unroll
            for (int r = 0; r < 4; r++)
                redS[wn * 256 + wm * 128 + i * 16 + quad * 4 + r] = sm[i][r];
    }
    __syncthreads();

    // ---- stage 2: y = P @ ctx^T per head (K=128), ctx from global (L2) ----
    const unsigned short* cg2 = ctxT + ((long)(b * NHEAD + hp * 2 + h) << 14);
    f32x4 acc2[8][4];
#pragma unroll
    for (int i = 0; i < 8; i++)
#pragma unroll
        for (int j = 0; j < 4; j++) { acc2[i][j][0] = 0.f; acc2[i][j][1] = 0.f; acc2[i][j][2] = 0.f; acc2[i][j][3] = 0.f; }
#pragma unroll
    for (int ks = 0; ks < 4; ks++) {
        bf16x8 bfr2[4];
#pragma unroll
        for (int j = 0; j < 4; j++)
            bfr2[j] = *(const bf16x8*)&cg2[((wn & 1) * 64 + j * 16 + l16) * 128 + ks * 32 + quad * 8];
#pragma unroll
        for (int i = 0; i < 8; i++) {
            bf16x8 af2 = *(const bf16x8*)&Pb[(wm * 128 + i * 16 + l16) * 264 + h * 128 + ks * 32 + quad * 8];
#pragma unroll
            for (int j = 0; j < 4; j++)
                acc2[i][j] = __builtin_amdgcn_mfma_f32_16x16x32_bf16(af2, bfr2[j], acc2[i][j], 0, 0, 0);
        }
    }

    // ---- epilogue: scale by 1/rowsum, write f32 ----
#pragma unroll
    for (int i = 0; i < 8; i++)
#pragma unroll
        for (int r = 0; r < 4; r++) {
            int row = wm * 128 + i * 16 + quad * 4 + r;
            float invd = 1.f / (redS[(h * 2) * 256 + row] + redS[(h * 2 + 1) * 256 + row]);
            float* op = out + (long)(m0 + row) * DDIM + hp * 256;
#pragma unroll
            for (int j = 0; j < 4; j++)
                op[wn * 64 + j * 16 + l16] = acc2[i][j][r] * invd;
        }
}

extern "C" void kernel_launch(void* const* d_in, const int* in_sizes, int n_in,
                              void* d_out, int out_size, void* d_ws, size_t ws_size,
                              hipStream_t stream) {
    (void)in_sizes; (void)n_in; (void)out_size; (void)ws_size;
    const float* x     = (const float*)d_in[0];
    const float* cond  = (const float*)d_in[1];
    const float* ln_g  = (const float*)d_in[2];
    const float* ln_b  = (const float*)d_in[3];
    const float* tln_g = (const float*)d_in[4];
    const float* tln_b = (const float*)d_in[5];
    const float* Wq    = (const float*)d_in[6];
    const float* bq    = (const float*)d_in[7];
    const float* Wk    = (const float*)d_in[8];
    const float* bk    = (const float*)d_in[9];
    const float* Wv    = (const float*)d_in[10];
    const float* bv    = (const float*)d_in[11];
    float* out = (float*)d_out;

    uint8_t* w8 = (uint8_t*)d_ws;
    unsigned short* xn   = (unsigned short*)w8;                  // 33,554,432 B
    unsigned short* cn   = (unsigned short*)(w8 + 33554432);     //  3,145,728
    unsigned short* wqT  = (unsigned short*)(w8 + 36700160);     //  2,097,152
    unsigned short* wkvT = (unsigned short*)(w8 + 38797312);     //  3,145,728
    float*          fk   = (float*)(w8 + 41943040);              //  8,388,608 (raw k f32)
    unsigned short* fvb  = (unsigned short*)(w8 + 50331648);     //  4,194,304 (v bf16)
    unsigned short* ctxT = (unsigned short*)(w8 + 56623104);     //  1,048,576

    // 1) LN(x), LN(cond), W^T x3
    prep<<<7168, 256, 0, stream>>>(x, ln_g, ln_b, cond, tln_g, tln_b,
                                   Wq, Wk, Wv, xn, cn, wqT, wkvT);
    // 2) k (f32) and v (bf16)
    gemm_kv<<<dim3(8, 16, 2), 256, 0, stream>>>(cn, wkvT, bk, bv, fk, fvb);
    // 3) ctx = softmax(k)^T v via MFMA, stats inlined, bf16 out
    ctx_mfma2s<<<dim3(4, 32), 256, 0, stream>>>(fk, fvb, ctxT);
    // 4) fused q-proj + softmax + @ctx, 256x256 8-wave deep-pipelined
    qfused2<<<256, 512, 0, stream>>>(xn, wqT, bq, ctxT, out);
}